// Round 15
// baseline (134.532 us; speedup 1.0000x reference)
//
#include <hip/hip_runtime.h>
#include <hip/hip_bf16.h>

// ConvolutionalAttention2D: B=16, C=256, N=H*W=4096.
// out = (Wo * (phiQ @ phiV^T)) @ phiK + bo, phiX = elu(Wx @ x)+1
// bf16 MFMA (16x16x32), fp32 accumulate.
// Round 15: kill k_pre's xT round-trip (96 MiB) — k_proj stages x f32 tiles
// LINEARLY (coalesced 512B rows, r9's bug fixed) and transposes in the
// fragment read (8x ds_read_b32 stride-512 + f2bf pack, XOR'd conflict-free).
// Rest = r13/r14 best config (XCD-swizzled k_qv/k_out, bf16 partials).

typedef short  bf16x8 __attribute__((ext_vector_type(8)));
typedef float  f32x4  __attribute__((ext_vector_type(4)));
typedef unsigned short u16x4 __attribute__((ext_vector_type(4)));

#define NB 16
#define NC 256
#define NN 4096

__device__ __forceinline__ unsigned short f2bf(float f) {
    union { float f; unsigned u; } v; v.f = f;
    unsigned r = v.u + 0x7FFFu + ((v.u >> 16) & 1u);
    return (unsigned short)(r >> 16);
}

__device__ __forceinline__ float bf2f(unsigned short h) {
    union { unsigned u; float f; } v; v.u = (unsigned)h << 16;
    return v.f;
}

__device__ __forceinline__ float phi_act(float v) {
    return v > 0.f ? v + 1.f : __expf(v);
}

__device__ __forceinline__ void gload_lds16(const void* g, void* l) {
    __builtin_amdgcn_global_load_lds(
        (const __attribute__((address_space(1))) void*)g,
        (__attribute__((address_space(3))) void*)l, 16, 0, 0);
}

// Stage a 128row x 64k bf16 tile (16 KB) into linear LDS with XOR-swizzled
// SOURCE address (both-sides swizzle; reads use frag_ld's matching XOR).
__device__ __forceinline__ void stage_tile(
    const unsigned short* __restrict__ src, int ld, int kb, char* lds, int t)
{
    const int kslot  = t & 7;
    const int rbase  = t >> 3;                         // 0..31
    const int srcOff = (kslot * 16) ^ ((rbase & 7) << 4);
    const int wbase  = (t >> 6) * 1024;                // wave-uniform
    #pragma unroll
    for (int i = 0; i < 4; ++i) {
        const int r = i * 32 + rbase;
        const char* g = (const char*)(src + (size_t)r * ld + kb) + srcOff;
        gload_lds16(g, lds + i * 4096 + wbase);
    }
}

// Swizzled fragment read: row-major [128][64] bf16, byte ^= ((row&7)<<4)
__device__ __forceinline__ bf16x8 frag_ld(const char* lds, int row, int kbyte) {
    return *(const bf16x8*)(lds + row * 128 + (kbyte ^ ((row & 7) << 4)));
}

// ---------------------------------------------------------------------------
// r2 2-barrier 128x128 engine — known good (qv/mproj/out).
// SWAP=false: acc[m][n] rows = A-dim (wr+m*16+q4+i), cols = B-dim (wc+n*16+c15)
// SWAP=true : acc[m][n] rows = B-dim (wc+n*16+q4+i), cols = A-dim (wr+m*16+c15)
// ---------------------------------------------------------------------------
template<bool SWAP>
__device__ __forceinline__ void gemm128(
    const unsigned short* __restrict__ A, int lda,
    const unsigned short* __restrict__ BT, int ldb,
    int k0, int nk, char* lsA, char* lsB, f32x4 (&acc)[4][4])
{
    const int t = threadIdx.x;
    const int lane = t & 63;
    const int w  = t >> 6;
    const int wr = (w >> 1) * 64, wc = (w & 1) * 64;
    const int q  = lane >> 4, c15 = lane & 15;

    for (int kt = 0; kt < nk; ++kt) {
        const int kb = k0 + kt * 64;
        if (kt) __syncthreads();            // prior reads done before overwrite
        stage_tile(A,  lda, kb, lsA, t);
        stage_tile(BT, ldb, kb, lsB, t);
        __syncthreads();                    // compiler drains vmcnt before barrier
        #pragma unroll
        for (int g = 0; g < 2; ++g) {
            const int kbyte = g * 64 + q * 16;
            bf16x8 af[4], bfr[4];
            #pragma unroll
            for (int m = 0; m < 4; ++m) af[m]  = frag_ld(lsA, wr + m * 16 + c15, kbyte);
            #pragma unroll
            for (int n = 0; n < 4; ++n) bfr[n] = frag_ld(lsB, wc + n * 16 + c15, kbyte);
            #pragma unroll
            for (int m = 0; m < 4; ++m)
                #pragma unroll
                for (int n = 0; n < 4; ++n)
                    acc[m][n] = SWAP
                        ? __builtin_amdgcn_mfma_f32_16x16x32_bf16(bfr[n], af[m], acc[m][n], 0, 0, 0)
                        : __builtin_amdgcn_mfma_f32_16x16x32_bf16(af[m], bfr[n], acc[m][n], 0, 0, 0);
        }
    }
}

// ---------------------------------------------------------------------------
// k_proj engine: A = W slab (bf16, gload_lds + XOR); B = x tile staged
// LINEARLY as [64 c][128 n] f32 (32 KB) with per-unit XOR ((c&24)<<1);
// transpose happens in the fragment read (8x ds_read_b32 stride 512B).
// ---------------------------------------------------------------------------
template<bool SWAP>
__device__ __forceinline__ void gemm_projx(
    const unsigned short* __restrict__ A,     // [128][256] weight slab
    const float* __restrict__ xb,             // x[b] + nt*128 ([c][n], ld=NN)
    char* lsA, char* lsB, f32x4 (&acc)[4][4])
{
    const int t = threadIdx.x, lane = t & 63, w = t >> 6;
    const int wr = (w >> 1) * 64, wc = (w & 1) * 64;
    const int q = lane >> 4, c15 = lane & 15;
    const int wbase = w * 1024;

    for (int kt = 0; kt < 4; ++kt) {
        if (kt) __syncthreads();            // prior reads done before overwrite
        stage_tile(A, NC, kt * 64, lsA, t); // A: 4 gloads (bf16)
        // B: x rows c = kt*64..+64, 128 n f32 = 32 KB, linear + unit XOR
        #pragma unroll
        for (int i = 0; i < 8; ++i) {
            const int u    = i * 256 + t;
            const int row  = u >> 5;        // c-local 0..63
            const int slot = u & 31;
            const char* g = (const char*)(xb + (size_t)(kt * 64 + row) * NN)
                          + ((slot * 16) ^ ((row & 24) << 1));
            gload_lds16(g, lsB + i * 4096 + wbase);
        }
        __syncthreads();                    // drains vmcnt
        #pragma unroll
        for (int g2 = 0; g2 < 2; ++g2) {
            const int c0 = g2 * 32 + q * 8;         // k-slice base (c-local)
            bf16x8 af[4], bfr[4];
            #pragma unroll
            for (int m = 0; m < 4; ++m)
                af[m] = frag_ld(lsA, wr + m * 16 + c15, g2 * 64 + q * 16);
            #pragma unroll
            for (int f = 0; f < 4; ++f) {
                const int nn = wc + f * 16 + c15;
                const char* bb = lsB + c0 * 512 + ((nn * 4) ^ ((c0 & 24) << 1));
                union { bf16x8 v; unsigned short e[8]; } pk;
                #pragma unroll
                for (int j = 0; j < 8; ++j)
                    pk.e[j] = f2bf(*(const float*)(bb + j * 512));
                bfr[f] = pk.v;
            }
            #pragma unroll
            for (int m = 0; m < 4; ++m)
                #pragma unroll
                for (int n = 0; n < 4; ++n)
                    acc[m][n] = SWAP
                        ? __builtin_amdgcn_mfma_f32_16x16x32_bf16(bfr[n], af[m], acc[m][n], 0, 0, 0)
                        : __builtin_amdgcn_mfma_f32_16x16x32_bf16(af[m], bfr[n], acc[m][n], 0, 0, 0);
        }
    }
}

// ---- K0: weights -> bf16 (x no longer preprocessed) ------------------------
__global__ __launch_bounds__(256) void k_wcvt(
    const float* __restrict__ Wq, const float* __restrict__ Wk,
    const float* __restrict__ Wv, const float* __restrict__ Wo,
    unsigned short* __restrict__ Wqkv, unsigned short* __restrict__ Wob)
{
    int i = blockIdx.x * 256 + threadIdx.x;        // 262144 total
    if      (i < 65536)  Wqkv[i] = f2bf(Wq[i]);
    else if (i < 131072) Wqkv[i] = f2bf(Wk[i - 65536]);
    else if (i < 196608) Wqkv[i] = f2bf(Wv[i - 131072]);
    else if (i < 262144) Wob[i - 196608] = f2bf(Wo[i - 196608]);
}

// ------ K1: [phiQ;phiK^T;phiV] = phi(Wqkv @ x); grid 16b*6mt*32nt -----------
__global__ __launch_bounds__(256) void k_proj(
    const unsigned short* __restrict__ Wqkv, const float* __restrict__ x,
    unsigned short* __restrict__ phiQ, unsigned short* __restrict__ phiKT,
    unsigned short* __restrict__ phiV)
{
    __shared__ __align__(16) char lds[49152];   // lsA 16K + lsB 32K -> 3 blk/CU
    const int bid = blockIdx.x;                    // 3072
    const int nt  = bid & 31;
    const int mt  = (bid >> 5) % 6;
    const int b   = bid / 192;
    const unsigned short* A = Wqkv + (size_t)mt * 128 * NC;
    const float* xb = x + (size_t)b * NC * NN + nt * 128;

    const int lane = threadIdx.x & 63;
    const int w    = threadIdx.x >> 6;
    const int wr   = (w >> 1) * 64, wc = (w & 1) * 64;
    const int q4   = (lane >> 4) * 4, c15 = lane & 15;
    const int p    = mt >> 1;                 // 0=Q, 1=K, 2=V

    f32x4 acc[4][4] = {};
    if (p == 1) {
        gemm_projx<false>(A, xb, lds, lds + 16384, acc);
        // phiKT[n][c]: regs span c -> packed u16x4 along c
        unsigned short* dst = phiKT + (size_t)b * NN * NC;
        const int cb = (mt & 1) * 128 + wr + q4;
        const int nb = nt * 128 + wc + c15;
        #pragma unroll
        for (int m = 0; m < 4; ++m)
            #pragma unroll
            for (int n = 0; n < 4; ++n) {
                u16x4 pk;
                #pragma unroll
                for (int i = 0; i < 4; ++i) pk[i] = f2bf(phi_act(acc[m][n][i]));
                *(u16x4*)(dst + (size_t)(nb + n * 16) * NC + cb + m * 16) = pk;
            }
    } else {
        gemm_projx<true>(A, xb, lds, lds + 16384, acc);
        // phi{Q,V}[c][n]: SWAP -> regs span n -> packed u16x4 along n
        unsigned short* dst = (p == 0 ? phiQ : phiV) + (size_t)b * NC * NN;
        const int ob = (mt & 1) * 128 + wr + c15;
        const int nb = nt * 128 + wc + q4;
        #pragma unroll
        for (int m = 0; m < 4; ++m)
            #pragma unroll
            for (int n = 0; n < 4; ++n) {
                u16x4 pk;
                #pragma unroll
                for (int i = 0; i < 4; ++i) pk[i] = f2bf(phi_act(acc[m][n][i]));
                *(u16x4*)(dst + (size_t)(ob + m * 16) * NN + nb + n * 16) = pk;
            }
    }
}

// ------ K2: qvT_part[s][b][d][c] bf16 partials, split-K=8, XCD swizzle ------
__global__ __launch_bounds__(256) void k_qv(
    const unsigned short* __restrict__ phiQ, const unsigned short* __restrict__ phiV,
    unsigned short* __restrict__ qvTp)
{
    __shared__ char lds[32768];
    const int bid = (blockIdx.x & 7) * 64 + (blockIdx.x >> 3);   // 512 = 8*64
    const int s = bid & 7, nt = (bid >> 3) & 1, mt = (bid >> 4) & 1, b = bid >> 5;
    const unsigned short* A  = phiQ + ((size_t)b * NC + mt * 128) * NN;
    const unsigned short* BT = phiV + ((size_t)b * NC + nt * 128) * NN;
    f32x4 acc[4][4] = {};
    gemm128<false>(A, NN, BT, NN, s * 512, 8, lds, lds + 16384, acc);

    const int lane = threadIdx.x & 63, w = threadIdx.x >> 6;
    const int wr = (w >> 1) * 64, wc = (w & 1) * 64;
    const int q4 = (lane >> 4) * 4, c15 = lane & 15;
    unsigned short* dst = qvTp + (((size_t)s * NB + b) << 16);
    const int c0 = mt * 128 + wr + q4;
    const int d0 = nt * 128 + wc + c15;
    #pragma unroll
    for (int m = 0; m < 4; ++m)
        #pragma unroll
        for (int n = 0; n < 4; ++n) {
            u16x4 pk;
            #pragma unroll
            for (int i = 0; i < 4; ++i) pk[i] = f2bf(acc[m][n][i]);
            *(u16x4*)(dst + (size_t)(d0 + n * 16) * NC + c0 + m * 16) = pk;
        }
}

// ------ K2b: qvT[b][d][c] bf16 = sum_s bf16 partials ------------------------
__global__ __launch_bounds__(256) void k_qvred(
    const unsigned short* __restrict__ p, unsigned short* __restrict__ qvT)
{
    const size_t i = (size_t)blockIdx.x * 256 + threadIdx.x;  // 262144 u16x4 units
    const u16x4* pv = (const u16x4*)p;
    f32x4 v = {0.f, 0.f, 0.f, 0.f};
    #pragma unroll
    for (int s = 0; s < 8; ++s) {
        u16x4 a = pv[i + (size_t)s * 262144];
        #pragma unroll
        for (int j = 0; j < 4; ++j) v[j] += bf2f(a[j]);
    }
    u16x4 o;
    #pragma unroll
    for (int j = 0; j < 4; ++j) o[j] = f2bf(v[j]);
    ((u16x4*)qvT)[i] = o;
}

// ------ K3: Mb[b][o][d] = Wo @ qv  (SWAP: regs span d) -----------------------
__global__ __launch_bounds__(256) void k_mproj(
    const unsigned short* __restrict__ Wob, const unsigned short* __restrict__ qvT,
    unsigned short* __restrict__ Mb)
{
    __shared__ char lds[32768];
    const int bid = blockIdx.x;                    // 64 blocks
    const int nt = bid & 1, mt = (bid >> 1) & 1, b = bid >> 2;
    const unsigned short* A  = Wob + mt * 128 * NC;
    const unsigned short* BT = qvT + ((size_t)b << 16) + nt * 128 * NC;
    f32x4 acc[4][4] = {};
    gemm128<true>(A, NC, BT, NC, 0, 4, lds, lds + 16384, acc);

    const int lane = threadIdx.x & 63, w = threadIdx.x >> 6;
    const int wr = (w >> 1) * 64, wc = (w & 1) * 64;
    const int q4 = (lane >> 4) * 4, c15 = lane & 15;
    unsigned short* dst = Mb + ((size_t)b << 16);
    const int ob = mt * 128 + wr + c15;
    const int db = nt * 128 + wc + q4;
    #pragma unroll
    for (int m = 0; m < 4; ++m)
        #pragma unroll
        for (int n = 0; n < 4; ++n) {
            u16x4 pk;
            #pragma unroll
            for (int i = 0; i < 4; ++i) pk[i] = f2bf(acc[m][n][i]);
            *(u16x4*)(dst + (size_t)(ob + m * 16) * NC + db + n * 16) = pk;
        }
}

// ------ K4: out[b][o][n] = Mb @ phiK + bo  (r2 form + XCD chunk swizzle) ----
__global__ __launch_bounds__(256) void k_out(
    const unsigned short* __restrict__ Mb, const unsigned short* __restrict__ phiKT,
    const float* __restrict__ bo, float* __restrict__ out)
{
    __shared__ char lds[32768];
    const int bid = (blockIdx.x & 7) * 128 + (blockIdx.x >> 3); // 1024 = 8*128
    const int nt = bid & 31, mt = (bid >> 5) & 1, b = bid >> 6;
    const unsigned short* A  = Mb + ((size_t)b << 16) + mt * 128 * NC;
    const unsigned short* BT = phiKT + (size_t)b * NN * NC + (size_t)nt * 128 * NC;
    f32x4 acc[4][4] = {};
    gemm128<true>(A, NC, BT, NC, 0, 4, lds, lds + 16384, acc);

    const int lane = threadIdx.x & 63, w = threadIdx.x >> 6;
    const int wr = (w >> 1) * 64, wc = (w & 1) * 64;
    const int q4 = (lane >> 4) * 4, c15 = lane & 15;
    float* dst = out + (size_t)b * NC * NN;
    #pragma unroll
    for (int m = 0; m < 4; ++m) {
        const int o  = mt * 128 + wr + m * 16 + c15;
        const float bb = bo[o];
        #pragma unroll
        for (int n = 0; n < 4; ++n) {
            f32x4 v = acc[m][n];
            #pragma unroll
            for (int i = 0; i < 4; ++i) v[i] += bb;
            *(f32x4*)(dst + (size_t)o * NN + nt * 128 + wc + n * 16 + q4) = v;
        }
    }
}

// ---------------------------------------------------------------------------
extern "C" void kernel_launch(void* const* d_in, const int* in_sizes, int n_in,
                              void* d_out, int out_size, void* d_ws, size_t ws_size,
                              hipStream_t stream)
{
    (void)in_sizes; (void)n_in; (void)out_size; (void)ws_size;
    const float* x  = (const float*)d_in[0];
    const float* Wq = (const float*)d_in[1];
    const float* Wk = (const float*)d_in[2];
    const float* Wv = (const float*)d_in[3];
    const float* Wo = (const float*)d_in[4];
    const float* bo = (const float*)d_in[5];
    float* out = (float*)d_out;

    char* ws = (char*)d_ws;
    size_t off = 0;
    auto alloc = [&](size_t bytes) {
        void* p = ws + off;
        off += (bytes + 255) & ~(size_t)255;
        return p;
    };
    unsigned short* phiQ  = (unsigned short*)alloc((size_t)NB * NC * NN * 2); // 32 MiB
    unsigned short* phiV  = (unsigned short*)alloc((size_t)NB * NC * NN * 2); // 32 MiB
    unsigned short* phiKT = (unsigned short*)alloc((size_t)NB * NN * NC * 2); // 32 MiB
    unsigned short* qvTp  = (unsigned short*)alloc((size_t)8 * NB * NC * NC * 2); // 16 MiB
    unsigned short* qvT   = (unsigned short*)alloc((size_t)NB * NC * NC * 2); //  2 MiB
    unsigned short* Mb    = (unsigned short*)alloc((size_t)NB * NC * NC * 2); //  2 MiB
    unsigned short* Wqkv  = (unsigned short*)alloc((size_t)768 * NC * 2);
    unsigned short* Wob   = (unsigned short*)alloc((size_t)NC * NC * 2);

    k_wcvt<<<1024, 256, 0, stream>>>(Wq, Wk, Wv, Wo, Wqkv, Wob);
    k_proj<<<3072, 256, 0, stream>>>(Wqkv, x, phiQ, phiKT, phiV);
    k_qv<<<512, 256, 0, stream>>>(phiQ, phiV, qvTp);
    k_qvred<<<1024, 256, 0, stream>>>(qvTp, qvT);
    k_mproj<<<64, 256, 0, stream>>>(Wob, qvT, Mb);
    k_out<<<1024, 256, 0, stream>>>(Mb, phiKT, bo, out);
}

// Round 16
// 118.753 us; speedup vs baseline: 1.1329x; 1.1329x over previous
//
#include <hip/hip_runtime.h>
#include <hip/hip_bf16.h>

// ConvolutionalAttention2D: B=16, C=256, N=H*W=4096.
// out = (Wo * (phiQ @ phiV^T)) @ phiK + bo, phiX = elu(Wx @ x)+1
// bf16 MFMA (16x16x32), fp32 accumulate.
// Round 16: LOCK-IN of the round-13 best configuration (118.8 us).
// Components (each the best measured variant over 15 rounds):
//  - k_pre: fused x-transpose (LDS, bank-safe) + weight convert
//  - k_proj: r2 2-barrier engine, gload_lds width-16 + XOR swizzle, 0 conflicts
//  - k_qv: split-K=8, bf16 partials, XCD chunk swizzle
//  - k_qvred: 8-partial reduce
//  - k_mproj: r2 engine
//  - k_out: r2 engine + XCD chunk swizzle
// Rejected by A/B: counted-vmcnt pipeline (r5-7), fat 128x256 tiles (r8,r10),
// A-in-VGPR (r3), in-GEMM x transpose (r9,r11,r15), proj XCD swizzle (r4,r14).

typedef short  bf16x8 __attribute__((ext_vector_type(8)));
typedef float  f32x4  __attribute__((ext_vector_type(4)));
typedef unsigned short u16x4 __attribute__((ext_vector_type(4)));

#define NB 16
#define NC 256
#define NN 4096

__device__ __forceinline__ unsigned short f2bf(float f) {
    union { float f; unsigned u; } v; v.f = f;
    unsigned r = v.u + 0x7FFFu + ((v.u >> 16) & 1u);
    return (unsigned short)(r >> 16);
}

__device__ __forceinline__ float bf2f(unsigned short h) {
    union { unsigned u; float f; } v; v.u = (unsigned)h << 16;
    return v.f;
}

__device__ __forceinline__ float phi_act(float v) {
    return v > 0.f ? v + 1.f : __expf(v);
}

__device__ __forceinline__ void gload_lds16(const void* g, void* l) {
    __builtin_amdgcn_global_load_lds(
        (const __attribute__((address_space(1))) void*)g,
        (__attribute__((address_space(3))) void*)l, 16, 0, 0);
}

// Stage a 128row x 64k bf16 tile (16 KB) into linear LDS with XOR-swizzled
// SOURCE address (both-sides swizzle; reads use frag_ld's matching XOR).
__device__ __forceinline__ void stage_tile(
    const unsigned short* __restrict__ src, int ld, int kb, char* lds, int t)
{
    const int kslot  = t & 7;
    const int rbase  = t >> 3;                         // 0..31
    const int srcOff = (kslot * 16) ^ ((rbase & 7) << 4);
    const int wbase  = (t >> 6) * 1024;                // wave-uniform
    #pragma unroll
    for (int i = 0; i < 4; ++i) {
        const int r = i * 32 + rbase;
        const char* g = (const char*)(src + (size_t)r * ld + kb) + srcOff;
        gload_lds16(g, lds + i * 4096 + wbase);
    }
}

// Swizzled fragment read: row-major [128][64] bf16, byte ^= ((row&7)<<4)
__device__ __forceinline__ bf16x8 frag_ld(const char* lds, int row, int kbyte) {
    return *(const bf16x8*)(lds + row * 128 + (kbyte ^ ((row & 7) << 4)));
}

// ---------------------------------------------------------------------------
// r2 2-barrier 128x128 engine — known good.
// SWAP=false: acc[m][n] rows = A-dim (wr+m*16+q4+i), cols = B-dim (wc+n*16+c15)
// SWAP=true : acc[m][n] rows = B-dim (wc+n*16+q4+i), cols = A-dim (wr+m*16+c15)
// ---------------------------------------------------------------------------
template<bool SWAP>
__device__ __forceinline__ void gemm128(
    const unsigned short* __restrict__ A, int lda,
    const unsigned short* __restrict__ BT, int ldb,
    int k0, int nk, char* lsA, char* lsB, f32x4 (&acc)[4][4])
{
    const int t = threadIdx.x;
    const int lane = t & 63;
    const int w  = t >> 6;
    const int wr = (w >> 1) * 64, wc = (w & 1) * 64;
    const int q  = lane >> 4, c15 = lane & 15;

    for (int kt = 0; kt < nk; ++kt) {
        const int kb = k0 + kt * 64;
        if (kt) __syncthreads();            // prior reads done before overwrite
        stage_tile(A,  lda, kb, lsA, t);
        stage_tile(BT, ldb, kb, lsB, t);
        __syncthreads();                    // compiler drains vmcnt before barrier
        #pragma unroll
        for (int g = 0; g < 2; ++g) {
            const int kbyte = g * 64 + q * 16;
            bf16x8 af[4], bfr[4];
            #pragma unroll
            for (int m = 0; m < 4; ++m) af[m]  = frag_ld(lsA, wr + m * 16 + c15, kbyte);
            #pragma unroll
            for (int n = 0; n < 4; ++n) bfr[n] = frag_ld(lsB, wc + n * 16 + c15, kbyte);
            #pragma unroll
            for (int m = 0; m < 4; ++m)
                #pragma unroll
                for (int n = 0; n < 4; ++n)
                    acc[m][n] = SWAP
                        ? __builtin_amdgcn_mfma_f32_16x16x32_bf16(bfr[n], af[m], acc[m][n], 0, 0, 0)
                        : __builtin_amdgcn_mfma_f32_16x16x32_bf16(af[m], bfr[n], acc[m][n], 0, 0, 0);
        }
    }
}

// ---- K0 (fused): xpose (blocks 0..4095) + weight convert (blocks 4096..5119)
__global__ __launch_bounds__(256) void k_pre(
    const float* __restrict__ x,
    const float* __restrict__ Wq, const float* __restrict__ Wk,
    const float* __restrict__ Wv, const float* __restrict__ Wo,
    unsigned short* __restrict__ xT,
    unsigned short* __restrict__ Wqkv, unsigned short* __restrict__ Wob)
{
    __shared__ float tile[64][68];
    const int id = blockIdx.x;
    if (id >= 4096) {
        int i = (id - 4096) * 256 + threadIdx.x;   // 262144 total
        if      (i < 65536)  Wqkv[i] = f2bf(Wq[i]);
        else if (i < 131072) Wqkv[i] = f2bf(Wk[i - 65536]);
        else if (i < 196608) Wqkv[i] = f2bf(Wv[i - 131072]);
        else                 Wob[i - 196608] = f2bf(Wo[i - 196608]);
        return;
    }
    const int b  = id >> 8;
    const int n0 = (id & 63) * 64, c0 = ((id >> 6) & 3) * 64;
    const int t  = threadIdx.x;
    const float* xp = x + ((size_t)b * NC + c0) * NN + n0;
    const int cc = t >> 4, nq = t & 15;
    #pragma unroll
    for (int j = 0; j < 4; ++j) {
        const int c = j * 16 + cc;
        f32x4 v = *(const f32x4*)(xp + (size_t)c * NN + nq * 4);
        *(f32x4*)&tile[c][nq * 4] = v;
    }
    __syncthreads();
    unsigned short* op = xT + ((size_t)b * NN + n0) * NC + c0;
    const int nn0 = t >> 4, cq = t & 15;
    #pragma unroll
    for (int j = 0; j < 4; ++j) {
        const int nn = j * 16 + nn0;
        u16x4 o;
        #pragma unroll
        for (int ii = 0; ii < 4; ++ii) o[ii] = f2bf(tile[cq * 4 + ii][nn]);
        *(u16x4*)(op + (size_t)nn * NC + cq * 4) = o;
    }
}

// ------ K1: [phiQ;phiK^T;phiV] = phi(Wqkv @ x); grid 16b*6mt*32nt (r2) ------
__global__ __launch_bounds__(256) void k_proj(
    const unsigned short* __restrict__ Wqkv, const unsigned short* __restrict__ xT,
    unsigned short* __restrict__ phiQ, unsigned short* __restrict__ phiKT,
    unsigned short* __restrict__ phiV)
{
    __shared__ char lds[32768];
    const int bid = blockIdx.x;                    // 3072
    const int nt  = bid & 31;
    const int mt  = (bid >> 5) % 6;
    const int b   = bid / 192;
    const unsigned short* A  = Wqkv + (size_t)mt * 128 * NC;
    const unsigned short* BT = xT + ((size_t)b * NN + nt * 128) * NC;

    const int lane = threadIdx.x & 63;
    const int w    = threadIdx.x >> 6;
    const int wr   = (w >> 1) * 64, wc = (w & 1) * 64;
    const int q4   = (lane >> 4) * 4, c15 = lane & 15;
    const int p    = mt >> 1;                 // 0=Q, 1=K, 2=V

    f32x4 acc[4][4] = {};
    if (p == 1) {
        gemm128<false>(A, NC, BT, NC, 0, 4, lds, lds + 16384, acc);
        // phiKT[n][c]: regs span c -> packed u16x4 along c
        unsigned short* dst = phiKT + (size_t)b * NN * NC;
        const int cb = (mt & 1) * 128 + wr + q4;
        const int nb = nt * 128 + wc + c15;
        #pragma unroll
        for (int m = 0; m < 4; ++m)
            #pragma unroll
            for (int n = 0; n < 4; ++n) {
                u16x4 pk;
                #pragma unroll
                for (int i = 0; i < 4; ++i) pk[i] = f2bf(phi_act(acc[m][n][i]));
                *(u16x4*)(dst + (size_t)(nb + n * 16) * NC + cb + m * 16) = pk;
            }
    } else {
        gemm128<true>(A, NC, BT, NC, 0, 4, lds, lds + 16384, acc);
        // phi{Q,V}[c][n]: SWAP -> regs span n -> packed u16x4 along n
        unsigned short* dst = (p == 0 ? phiQ : phiV) + (size_t)b * NC * NN;
        const int ob = (mt & 1) * 128 + wr + c15;
        const int nb = nt * 128 + wc + q4;
        #pragma unroll
        for (int m = 0; m < 4; ++m)
            #pragma unroll
            for (int n = 0; n < 4; ++n) {
                u16x4 pk;
                #pragma unroll
                for (int i = 0; i < 4; ++i) pk[i] = f2bf(phi_act(acc[m][n][i]));
                *(u16x4*)(dst + (size_t)(ob + m * 16) * NN + nb + n * 16) = pk;
            }
    }
}

// ------ K2: qvT_part[s][b][d][c] bf16 partials, split-K=8, XCD swizzle ------
__global__ __launch_bounds__(256) void k_qv(
    const unsigned short* __restrict__ phiQ, const unsigned short* __restrict__ phiV,
    unsigned short* __restrict__ qvTp)
{
    __shared__ char lds[32768];
    const int bid = (blockIdx.x & 7) * 64 + (blockIdx.x >> 3);   // 512 = 8*64
    const int s = bid & 7, nt = (bid >> 3) & 1, mt = (bid >> 4) & 1, b = bid >> 5;
    const unsigned short* A  = phiQ + ((size_t)b * NC + mt * 128) * NN;
    const unsigned short* BT = phiV + ((size_t)b * NC + nt * 128) * NN;
    f32x4 acc[4][4] = {};
    gemm128<false>(A, NN, BT, NN, s * 512, 8, lds, lds + 16384, acc);

    const int lane = threadIdx.x & 63, w = threadIdx.x >> 6;
    const int wr = (w >> 1) * 64, wc = (w & 1) * 64;
    const int q4 = (lane >> 4) * 4, c15 = lane & 15;
    unsigned short* dst = qvTp + (((size_t)s * NB + b) << 16);
    const int c0 = mt * 128 + wr + q4;
    const int d0 = nt * 128 + wc + c15;
    #pragma unroll
    for (int m = 0; m < 4; ++m)
        #pragma unroll
        for (int n = 0; n < 4; ++n) {
            u16x4 pk;
            #pragma unroll
            for (int i = 0; i < 4; ++i) pk[i] = f2bf(acc[m][n][i]);
            *(u16x4*)(dst + (size_t)(d0 + n * 16) * NC + c0 + m * 16) = pk;
        }
}

// ------ K2b: qvT[b][d][c] bf16 = sum_s bf16 partials ------------------------
__global__ __launch_bounds__(256) void k_qvred(
    const unsigned short* __restrict__ p, unsigned short* __restrict__ qvT)
{
    const size_t i = (size_t)blockIdx.x * 256 + threadIdx.x;  // 262144 u16x4 units
    const u16x4* pv = (const u16x4*)p;
    f32x4 v = {0.f, 0.f, 0.f, 0.f};
    #pragma unroll
    for (int s = 0; s < 8; ++s) {
        u16x4 a = pv[i + (size_t)s * 262144];
        #pragma unroll
        for (int j = 0; j < 4; ++j) v[j] += bf2f(a[j]);
    }
    u16x4 o;
    #pragma unroll
    for (int j = 0; j < 4; ++j) o[j] = f2bf(v[j]);
    ((u16x4*)qvT)[i] = o;
}

// ------ K3: Mb[b][o][d] = Wo @ qv  (SWAP: regs span d) -----------------------
__global__ __launch_bounds__(256) void k_mproj(
    const unsigned short* __restrict__ Wob, const unsigned short* __restrict__ qvT,
    unsigned short* __restrict__ Mb)
{
    __shared__ char lds[32768];
    const int bid = blockIdx.x;                    // 64 blocks
    const int nt = bid & 1, mt = (bid >> 1) & 1, b = bid >> 2;
    const unsigned short* A  = Wob + mt * 128 * NC;
    const unsigned short* BT = qvT + ((size_t)b << 16) + nt * 128 * NC;
    f32x4 acc[4][4] = {};
    gemm128<true>(A, NC, BT, NC, 0, 4, lds, lds + 16384, acc);

    const int lane = threadIdx.x & 63, w = threadIdx.x >> 6;
    const int wr = (w >> 1) * 64, wc = (w & 1) * 64;
    const int q4 = (lane >> 4) * 4, c15 = lane & 15;
    unsigned short* dst = Mb + ((size_t)b << 16);
    const int ob = mt * 128 + wr + c15;
    const int db = nt * 128 + wc + q4;
    #pragma unroll
    for (int m = 0; m < 4; ++m)
        #pragma unroll
        for (int n = 0; n < 4; ++n) {
            u16x4 pk;
            #pragma unroll
            for (int i = 0; i < 4; ++i) pk[i] = f2bf(acc[m][n][i]);
            *(u16x4*)(dst + (size_t)(ob + m * 16) * NC + db + n * 16) = pk;
        }
}

// ------ K4: out[b][o][n] = Mb @ phiK + bo  (r2 form + XCD chunk swizzle) ----
__global__ __launch_bounds__(256) void k_out(
    const unsigned short* __restrict__ Mb, const unsigned short* __restrict__ phiKT,
    const float* __restrict__ bo, float* __restrict__ out)
{
    __shared__ char lds[32768];
    const int bid = (blockIdx.x & 7) * 128 + (blockIdx.x >> 3); // 1024 = 8*128
    const int nt = bid & 31, mt = (bid >> 5) & 1, b = bid >> 6;
    const unsigned short* A  = Mb + ((size_t)b << 16) + mt * 128 * NC;
    const unsigned short* BT = phiKT + (size_t)b * NN * NC + (size_t)nt * 128 * NC;
    f32x4 acc[4][4] = {};
    gemm128<true>(A, NC, BT, NC, 0, 4, lds, lds + 16384, acc);

    const int lane = threadIdx.x & 63, w = threadIdx.x >> 6;
    const int wr = (w >> 1) * 64, wc = (w & 1) * 64;
    const int q4 = (lane >> 4) * 4, c15 = lane & 15;
    float* dst = out + (size_t)b * NC * NN;
    #pragma unroll
    for (int m = 0; m < 4; ++m) {
        const int o  = mt * 128 + wr + m * 16 + c15;
        const float bb = bo[o];
        #pragma unroll
        for (int n = 0; n < 4; ++n) {
            f32x4 v = acc[m][n];
            #pragma unroll
            for (int i = 0; i < 4; ++i) v[i] += bb;
            *(f32x4*)(dst + (size_t)o * NN + nt * 128 + wc + n * 16 + q4) = v;
        }
    }
}

// ---------------------------------------------------------------------------
extern "C" void kernel_launch(void* const* d_in, const int* in_sizes, int n_in,
                              void* d_out, int out_size, void* d_ws, size_t ws_size,
                              hipStream_t stream)
{
    (void)in_sizes; (void)n_in; (void)out_size; (void)ws_size;
    const float* x  = (const float*)d_in[0];
    const float* Wq = (const float*)d_in[1];
    const float* Wk = (const float*)d_in[2];
    const float* Wv = (const float*)d_in[3];
    const float* Wo = (const float*)d_in[4];
    const float* bo = (const float*)d_in[5];
    float* out = (float*)d_out;

    char* ws = (char*)d_ws;
    size_t off = 0;
    auto alloc = [&](size_t bytes) {
        void* p = ws + off;
        off += (bytes + 255) & ~(size_t)255;
        return p;
    };
    unsigned short* xT    = (unsigned short*)alloc((size_t)NB * NN * NC * 2); // 32 MiB
    unsigned short* phiQ  = (unsigned short*)alloc((size_t)NB * NC * NN * 2); // 32 MiB
    unsigned short* phiV  = (unsigned short*)alloc((size_t)NB * NC * NN * 2); // 32 MiB
    unsigned short* phiKT = (unsigned short*)alloc((size_t)NB * NN * NC * 2); // 32 MiB
    unsigned short* qvT   = (unsigned short*)alloc((size_t)NB * NC * NC * 2); //  2 MiB
    unsigned short* Mb    = (unsigned short*)alloc((size_t)NB * NC * NC * 2); //  2 MiB
    unsigned short* Wqkv  = (unsigned short*)alloc((size_t)768 * NC * 2);
    unsigned short* Wob   = (unsigned short*)alloc((size_t)NC * NC * 2);
    unsigned short* qvTp = (unsigned short*)xT; // alias: xT dead after k_proj;
                                                // 8*16*64K*2B = 16 MiB

    k_pre<<<5120, 256, 0, stream>>>(x, Wq, Wk, Wv, Wo, xT, Wqkv, Wob);
    k_proj<<<3072, 256, 0, stream>>>(Wqkv, xT, phiQ, phiKT, phiV);
    k_qv<<<512, 256, 0, stream>>>(phiQ, phiV, qvTp);
    k_qvred<<<1024, 256, 0, stream>>>(qvTp, qvT);
    k_mproj<<<64, 256, 0, stream>>>(Wob, qvT, Mb);
    k_out<<<1024, 256, 0, stream>>>(Mb, phiKT, bo, out);
}